// Round 8
// baseline (104.316 us; speedup 1.0000x reference)
//
#include <hip/hip_runtime.h>
#include <hip/hip_bf16.h>

// Problem constants (from reference)
#define BATCH      8
#define S_BYTES    8192
#define NUM_EMB    384
#define BYTE_DIM   128
#define EMB_DIM    1024
#define NUM_TOKENS 2048
#define SCALE_F    11.313708498984761f   // sqrt(128)

#define M_TOTAL (BATCH * NUM_TOKENS)     // 16384 rows into the GEMM
#define SEG_STRIDE 2064                  // 2049 entries padded

typedef __bf16 bf16x8 __attribute__((ext_vector_type(8)));
typedef float  floatx4 __attribute__((ext_vector_type(4)));

// ---------------------------------------------------------------------------
// Kernel A (fused): blockIdx < 256  -> segment-boundary precompute
//                   blockIdx >= 256 -> out_proj_w fp32 -> bf16 convert
// (byte-identical to R6)
// ---------------------------------------------------------------------------
__global__ __launch_bounds__(256) void prep_kernel(
    const int* __restrict__ bg,           // [B, S_BYTES] sorted per row
    int* __restrict__ seg,                // [B, SEG_STRIDE]
    const float* __restrict__ w,          // [EMB_DIM, BYTE_DIM] fp32
    __hip_bfloat16* __restrict__ wb)      // [EMB_DIM, BYTE_DIM] bf16
{
    if (blockIdx.x < 256) {
        const int gid = blockIdx.x * 256 + threadIdx.x;   // 0..65535
        const int b = gid >> 13;
        const int i = gid & (S_BYTES - 1);
        const int g  = bg[gid];
        const int gp = (i == 0) ? -1 : bg[gid - 1];
        int* __restrict__ srow = seg + b * SEG_STRIDE;
        for (int t = gp + 1; t <= g; ++t) srow[t] = i;
        if (i == S_BYTES - 1) {
            for (int t = g + 1; t <= NUM_TOKENS; ++t) srow[t] = S_BYTES;
        }
    } else {
        const int i = ((blockIdx.x - 256) * 256 + threadIdx.x) * 4;  // 128 blocks
        const float4 v = *(const float4*)(w + i);
        wb[i + 0] = __float2bfloat16(v.x);
        wb[i + 1] = __float2bfloat16(v.y);
        wb[i + 2] = __float2bfloat16(v.z);
        wb[i + 3] = __float2bfloat16(v.w);
    }
}

// ---------------------------------------------------------------------------
// Kernel B (fused pool + GEMM, NO atomics): grid = 512 = 128 mb x 4 groups.
// Each block:
//  1. register-pools its 128-token A-tile: 8 sub-waves of 32 lanes; each sub
//     handles 16 tokens sequentially (float4 gather per lane, fp32 sum in
//     registers — same loop as the proven R6 pool), writes bf16 to LDS sA.
//  2. loops over 2 N-tiles (nb = group*2 + q): stage B (bf16, 16B/thread),
//     64x64/wave MFMA (4x4 accs), R6-style scattered fp32 stores
//     (L2-line-optimal: 4 x 64B lines per store instr — R7 post-mortem).
// LDS 64 KB -> 2 blocks/CU; co-resident pairs share mb -> warm L1 on the
// duplicated pool gathers. Pool duplication is 4x (parallel, overlapped).
// A-frag: A[m = lane&15][k = quad*8 + j]; C/D: col = lane&15, row = quad*4+reg.
// ---------------------------------------------------------------------------
__global__ __launch_bounds__(256) void pool_gemm_kernel(
    const int* __restrict__ x,                 // [B, S_BYTES]
    const int* __restrict__ seg,               // [B, SEG_STRIDE]
    const float* __restrict__ emb,             // [NUM_EMB, BYTE_DIM] fp32
    const __hip_bfloat16* __restrict__ wb,     // [EMB_DIM, BYTE_DIM] bf16
    float* __restrict__ out)                   // [M_TOTAL, EMB_DIM] fp32
{
    __shared__ __hip_bfloat16 sA[128 * 128];   // 32 KB MFMA A-tile [m][k]
    __shared__ __hip_bfloat16 sB[128 * 128];   // 32 KB MFMA B-tile [n][k]
    __shared__ int sseg[129];

    const int mb    = blockIdx.x & 127;        // fast -> XCD spread
    const int group = blockIdx.x >> 7;         // 0..3 -> nb pair
    const int b     = mb >> 4;
    const int t0    = (mb & 15) << 7;          // first token of this M-tile
    const int m0    = mb * 128;
    const int tid   = threadIdx.x;

    if (tid < 129) sseg[tid] = seg[b * SEG_STRIDE + t0 + tid];
    __syncthreads();

    // ---- phase 1: register pooling, 8 subs x 16 tokens ----
    {
        const int sub  = tid >> 5;             // 0..7
        const int lane = tid & 31;
        const int* __restrict__ xrow = x + b * S_BYTES;
        const float4* __restrict__ embv = (const float4*)emb;   // [NUM_EMB][32]

        for (int k = 0; k < 16; ++k) {
            const int tl = sub + k * 8;        // local token 0..127
            const int s = sseg[tl];
            const int e = sseg[tl + 1];
            const int cnt = e - s;

            float4 sum = {0.f, 0.f, 0.f, 0.f};
            #pragma unroll 4
            for (int i = s; i < e; ++i) {
                const int ei = xrow[i];                 // broadcast
                const float4 v = embv[ei * 32 + lane];  // 16 B/lane coalesced
                sum.x += v.x; sum.y += v.y; sum.z += v.z; sum.w += v.w;
            }
            const float inv = SCALE_F / (float)(cnt > 1 ? cnt : 1);

            __hip_bfloat16 o[4];
            o[0] = __float2bfloat16(sum.x * inv);
            o[1] = __float2bfloat16(sum.y * inv);
            o[2] = __float2bfloat16(sum.z * inv);
            o[3] = __float2bfloat16(sum.w * inv);
            *(uint2*)(sA + tl * BYTE_DIM + lane * 4) = *(const uint2*)o;  // 8 B/lane
        }
    }

    const int wave = tid >> 6;
    const int lane = tid & 63;
    const int wm = wave >> 1;        // 0..1
    const int wn = wave & 1;         // 0..1
    const int r    = lane & 15;
    const int quad = lane >> 4;

    // ---- phase 2: two N-tiles of 128 ----
    for (int q = 0; q < 2; ++q) {
        const int n0 = (group * 2 + q) * 128;

        __syncthreads();   // sA ready (q=0) / previous sB reads done (q=1)
        {
            const bf16x8* __restrict__ gB = (const bf16x8*)(wb + (size_t)n0 * BYTE_DIM);
            bf16x8* __restrict__ lB = (bf16x8*)sB;
            #pragma unroll
            for (int i = 0; i < 8; ++i) lB[tid + i * 256] = gB[tid + i * 256];
        }
        __syncthreads();

        floatx4 acc[4][4] = {};
        #pragma unroll
        for (int kk = 0; kk < 4; ++kk) {
            bf16x8 af[4], bfr[4];
            #pragma unroll
            for (int i = 0; i < 4; ++i)
                af[i] = *(const bf16x8*)(sA + (wm * 64 + i * 16 + r) * BYTE_DIM + kk * 32 + quad * 8);
            #pragma unroll
            for (int j = 0; j < 4; ++j)
                bfr[j] = *(const bf16x8*)(sB + (wn * 64 + j * 16 + r) * BYTE_DIM + kk * 32 + quad * 8);
            #pragma unroll
            for (int i = 0; i < 4; ++i)
                #pragma unroll
                for (int j = 0; j < 4; ++j)
                    acc[i][j] = __builtin_amdgcn_mfma_f32_16x16x32_bf16(af[i], bfr[j], acc[i][j], 0, 0, 0);
        }

        #pragma unroll
        for (int i = 0; i < 4; ++i) {
            const int mrow = m0 + wm * 64 + i * 16 + quad * 4;
            #pragma unroll
            for (int j = 0; j < 4; ++j) {
                const int ncol = n0 + wn * 64 + j * 16 + r;
                float* __restrict__ p = out + (size_t)mrow * EMB_DIM + ncol;
                #pragma unroll
                for (int reg = 0; reg < 4; ++reg)
                    p[(size_t)reg * EMB_DIM] = acc[i][j][reg];
            }
        }
    }
}

extern "C" void kernel_launch(void* const* d_in, const int* in_sizes, int n_in,
                              void* d_out, int out_size, void* d_ws, size_t ws_size,
                              hipStream_t stream) {
    const int*   x   = (const int*)d_in[0];     // [8, 8192] int32
    const int*   bg  = (const int*)d_in[1];     // [8, 8192] int32 (sorted rows)
    const float* emb = (const float*)d_in[2];   // [384, 128] fp32
    const float* w   = (const float*)d_in[3];   // [1024, 128] fp32
    float*       out = (float*)d_out;           // [16384, 1024] fp32

    // ws layout: wb bf16 [1024,128] (256 KB) | seg int [8][2064]
    __hip_bfloat16* wb  = (__hip_bfloat16*)d_ws;
    int*            seg = (int*)((char*)d_ws + (size_t)EMB_DIM * BYTE_DIM * 2);

    prep_kernel<<<256 + (EMB_DIM * BYTE_DIM) / (256 * 4), 256, 0, stream>>>(bg, seg, w, wb);
    // 128 mb x 4 groups; each block does 2 N-tiles
    pool_gemm_kernel<<<512, 256, 0, stream>>>(x, seg, emb, wb, out);
}